// Round 2
// baseline (240.660 us; speedup 1.0000x reference)
//
#include <hip/hip_runtime.h>
#include <hip/hip_bf16.h>

#define LSEQ 4096
#define NH 32
#define NEP 32
#define NEPH 1024
#define CLEN 16
#define NCHUNK 256

typedef __attribute__((ext_vector_type(8))) short bf16x8;
typedef __attribute__((ext_vector_type(4))) float f32x4;

__device__ __forceinline__ void gl_lds16(const void* g, void* l) {
  __builtin_amdgcn_global_load_lds(
      (const __attribute__((address_space(1))) unsigned int*)g,
      (__attribute__((address_space(3))) unsigned int*)l, 16, 0, 0);
}

__device__ __forceinline__ float silu_f(float v) { return v / (1.0f + __expf(-v)); }

// ---------------- per-channel constants ----------------
// consts layout: [0]=A0r [1024]=A0i [2048]=cos(A0i) [3072]=sin(A0i) [4096]=Bcr [5120]=Bci
__global__ void k_const(const float* __restrict__ Lre, const float* __restrict__ Lim,
                        const float* __restrict__ lst, float* __restrict__ consts) {
  int c = threadIdx.x;  // 1024
  int h = c >> 5;
  float s = __expf(lst[h]);
  float lr = Lre[c], li = Lim[c];
  float er = __expf(lr * s);
  float A0r = er * cosf(li * s);
  float A0i = er * sinf(li * s);
  float den = lr * lr + li * li;
  float nr = A0r - 1.0f, ni = A0i;
  consts[c] = A0r;
  consts[1024 + c] = A0i;
  consts[2048 + c] = cosf(A0i);
  consts[3072 + c] = sinf(A0i);
  consts[4096 + c] = (nr * lr + ni * li) / den;
  consts[5120 + c] = (ni * lr - nr * li) / den;
}

// ---------------- x projections ----------------
// Bp_pad: bf16 (LSEQ+3, 1024), rows 1..LSEQ = x@Wb+bb ; Lam = silu(x@Wl+bl) f32 (L,1024)
// gt = silu(x@Wg+bg) (L,32) ; Dp = softplus(x@Wd+bd) (L,)
__global__ __launch_bounds__(256) void k_proj(
    const float* __restrict__ x, const float* __restrict__ Wb, const float* __restrict__ bb,
    const float* __restrict__ Wl, const float* __restrict__ bl,
    const float* __restrict__ Wg, const float* __restrict__ bg,
    const float* __restrict__ Wd, const float* __restrict__ bd,
    __hip_bfloat16* __restrict__ Bp, float* __restrict__ Lam,
    float* __restrict__ gt, float* __restrict__ Dp) {
  __shared__ float xs[8][32];
  int tid = threadIdx.x;
  int l0 = blockIdx.x * 8;
  xs[tid >> 5][tid & 31] = x[l0 * 32 + tid];
  __syncthreads();

  float accB[4][8], accL[4][8];
#pragma unroll
  for (int cc = 0; cc < 4; cc++)
#pragma unroll
    for (int ll = 0; ll < 8; ll++) { accB[cc][ll] = 0.f; accL[cc][ll] = 0.f; }

#pragma unroll 8
  for (int h = 0; h < 32; h++) {
    float wb[4], wl[4];
#pragma unroll
    for (int cc = 0; cc < 4; cc++) {
      wb[cc] = Wb[h * 1024 + cc * 256 + tid];
      wl[cc] = Wl[h * 1024 + cc * 256 + tid];
    }
#pragma unroll
    for (int ll = 0; ll < 8; ll++) {
      float xv = xs[ll][h];
#pragma unroll
      for (int cc = 0; cc < 4; cc++) {
        accB[cc][ll] = fmaf(wb[cc], xv, accB[cc][ll]);
        accL[cc][ll] = fmaf(wl[cc], xv, accL[cc][ll]);
      }
    }
  }
#pragma unroll
  for (int cc = 0; cc < 4; cc++) {
    int c = cc * 256 + tid;
    float bbv = bb[c], blv = bl[c];
#pragma unroll
    for (int ll = 0; ll < 8; ll++) {
      int l = l0 + ll;
      Bp[(size_t)(l + 1) * 1024 + c] = __float2bfloat16(accB[cc][ll] + bbv);
      Lam[(size_t)l * 1024 + c] = silu_f(accL[cc][ll] + blv);
    }
  }
  // gt: 8 l x 32 j = 256 threads, one each
  {
    int ll = tid >> 5, jh = tid & 31;
    float a = 0.f;
#pragma unroll
    for (int h = 0; h < 32; h++) a = fmaf(xs[ll][h], Wg[h * 32 + jh], a);
    a += bg[jh];
    gt[(l0 + ll) * 32 + jh] = silu_f(a);
  }
  if (tid < 8) {
    float a = 0.f;
#pragma unroll
    for (int h = 0; h < 32; h++) a = fmaf(xs[tid][h], Wd[h], a);
    a += bd[0];
    Dp[l0 + tid] = (a > 20.f) ? a : log1pf(__expf(a));
  }
}

// ---------------- transpose conv_w (4096x1024 f32) -> WT bf16 (1024x4096) ----------------
__global__ __launch_bounds__(256) void k_transpose(const float* __restrict__ w,
                                                   __hip_bfloat16* __restrict__ WT) {
  __shared__ float t[32][33];
  int k0 = blockIdx.x * 32;  // over 4096
  int n0 = blockIdx.y * 32;  // over 1024
  int r = threadIdx.x >> 5, cidx = threadIdx.x & 31;
#pragma unroll
  for (int i = 0; i < 4; i++)
    t[r + i * 8][cidx] = w[(size_t)(k0 + r + i * 8) * 1024 + n0 + cidx];
  __syncthreads();
#pragma unroll
  for (int i = 0; i < 4; i++) {
    int a = r + i * 8;  // n within tile
    WT[(size_t)(n0 + a) * 4096 + k0 + cidx] = __float2bfloat16(t[cidx][a]);
  }
}

// ---------------- conv-as-GEMM: (4096 x 4096) @ (4096 x 1024), epilogue silu -> B_act ----------------
#define BM 128
#define BN 64
#define BK 64
__global__ __launch_bounds__(256) void k_conv_gemm(const __hip_bfloat16* __restrict__ A,
                                                   const __hip_bfloat16* __restrict__ BT,
                                                   const float* __restrict__ cb,
                                                   float* __restrict__ Bact) {
  __shared__ __align__(16) __hip_bfloat16 As[BM * BK];
  __shared__ __align__(16) __hip_bfloat16 Bs[BN * BK];
  int tid = threadIdx.x;
  int row0 = blockIdx.y * BM;
  int col0 = blockIdx.x * BN;
  int lane = tid & 63, wid = tid >> 6;
  int wr = wid >> 1, wc = wid & 1;
  int rA = lane & 15, kg = lane >> 4;
  unsigned wbase = tid & ~63u;

  f32x4 acc[4][2];
#pragma unroll
  for (int m = 0; m < 4; m++)
#pragma unroll
    for (int n = 0; n < 2; n++) acc[m][n] = (f32x4){0.f, 0.f, 0.f, 0.f};

  for (int ks = 0; ks < 64; ks++) {
    int k0 = ks * 64;
#pragma unroll
    for (int i = 0; i < 4; i++) {
      int chunk = i * 256 + tid;
      int m = chunk >> 3, ko = (chunk & 7) * 8;
      gl_lds16(A + (size_t)(row0 + m) * 1024 + k0 + ko, (void*)(As + (size_t)(i * 256 + wbase) * 8));
    }
#pragma unroll
    for (int i = 0; i < 2; i++) {
      int chunk = i * 256 + tid;
      int n = chunk >> 3, ko = (chunk & 7) * 8;
      gl_lds16(BT + (size_t)(col0 + n) * 4096 + k0 + ko, (void*)(Bs + (size_t)(i * 256 + wbase) * 8));
    }
    __syncthreads();

    bf16x8 af[4][2], bfg[2][2];
#pragma unroll
    for (int m = 0; m < 4; m++)
#pragma unroll
      for (int kk = 0; kk < 2; kk++)
        af[m][kk] = *(const bf16x8*)(As + (wr * 64 + m * 16 + rA) * 64 + kk * 32 + kg * 8);
#pragma unroll
    for (int n = 0; n < 2; n++)
#pragma unroll
      for (int kk = 0; kk < 2; kk++)
        bfg[n][kk] = *(const bf16x8*)(Bs + (wc * 32 + n * 16 + rA) * 64 + kk * 32 + kg * 8);
#pragma unroll
    for (int m = 0; m < 4; m++)
#pragma unroll
      for (int n = 0; n < 2; n++)
#pragma unroll
        for (int kk = 0; kk < 2; kk++)
          acc[m][n] = __builtin_amdgcn_mfma_f32_16x16x32_bf16(af[m][kk], bfg[n][kk], acc[m][n], 0, 0, 0);
    __syncthreads();
  }
  // epilogue: B_act = silu(acc + conv_b)
#pragma unroll
  for (int m = 0; m < 4; m++)
#pragma unroll
    for (int n = 0; n < 2; n++) {
      int col = col0 + wc * 32 + n * 16 + (lane & 15);
      float cbv = cb[col];
#pragma unroll
      for (int r = 0; r < 4; r++) {
        int row = row0 + wr * 64 + m * 16 + (lane >> 4) * 4 + r;
        float v = acc[m][n][r] + cbv;
        Bact[(size_t)row * 1024 + col] = silu_f(v);
      }
    }
}

// ---------------- scan phase 1: per (channel, chunk) local scan ----------------
__global__ __launch_bounds__(256) void k_scan1(const float* __restrict__ consts,
                                               const float* __restrict__ Lam,
                                               const float* __restrict__ Bact,
                                               const float* __restrict__ Bin,
                                               float2* __restrict__ Acum,
                                               float2* __restrict__ Bloc) {
  int tid = threadIdx.x;
  int cgrp = blockIdx.x & 3;
  int chunk = blockIdx.x >> 2;
  int c = cgrp * 256 + tid;
  int j = c & 31;
  float A0r = consts[c], cz = consts[2048 + c], sz = consts[3072 + c];
  float Bcr = consts[4096 + c], Bci = consts[5120 + c];
  float ar = 1.f, ai = 0.f, br = 0.f, bi = 0.f;
  int l = chunk * CLEN;
  for (int it = 0; it < CLEN; it++, l++) {
    float La = Lam[(size_t)l * 1024 + c];
    float Ba = Bact[(size_t)l * 1024 + c];
    float2 bt = *(const float2*)(Bin + (size_t)l * 64 + j * 2);
    float e = __expf(A0r + La);
    float wr = fmaf(e, cz, 1.0f), wi = e * sz;
    float Ar = 0.5f * __logf(fmaf(wr, wr, wi * wi));
    float Ai = atan2f(wi, wr);
    float pr = Bcr * bt.x - Bci * bt.y;
    float pi = Bcr * bt.y + Bci * bt.x;
    float Bur = pr * Ba, Bui = pi * Ba;
    float nbr = Ar * br - Ai * bi + Bur;
    float nbi = Ar * bi + Ai * br + Bui;
    br = nbr; bi = nbi;
    float nar = Ar * ar - Ai * ai;
    float nai = Ar * ai + Ai * ar;
    ar = nar; ai = nai;
    Acum[(size_t)l * 1024 + c] = make_float2(ar, ai);
    Bloc[(size_t)l * 1024 + c] = make_float2(br, bi);
  }
}

// ---------------- scan phase 2: carries per (chunk, channel) ----------------
__global__ __launch_bounds__(64) void k_scan2(const float2* __restrict__ Acum,
                                              const float2* __restrict__ Bloc,
                                              float2* __restrict__ Carry) {
  int c = blockIdx.x;       // 1024 channels
  int lane = threadIdx.x;   // 64
  float mAr = 1.f, mAi = 0.f, mBr = 0.f, mBi = 0.f;
  float pr[4], pi[4], qr[4], qi[4];
#pragma unroll
  for (int u = 0; u < 4; u++) {
    pr[u] = mAr; pi[u] = mAi; qr[u] = mBr; qi[u] = mBi;
    int ck = lane * 4 + u;
    size_t le = (size_t)(ck * CLEN + CLEN - 1) * 1024 + c;
    float2 ga = Acum[le];
    float2 gb = Bloc[le];
    float nAr = ga.x * mAr - ga.y * mAi;
    float nAi = ga.x * mAi + ga.y * mAr;
    float nBr = ga.x * mBr - ga.y * mBi + gb.x;
    float nBi = ga.x * mBi + ga.y * mBr + gb.y;
    mAr = nAr; mAi = nAi; mBr = nBr; mBi = nBi;
  }
  float SAr = mAr, SAi = mAi, SBr = mBr, SBi = mBi;
#pragma unroll
  for (int d = 1; d < 64; d <<= 1) {
    float tAr = __shfl_up(SAr, (unsigned)d, 64);
    float tAi = __shfl_up(SAi, (unsigned)d, 64);
    float tBr = __shfl_up(SBr, (unsigned)d, 64);
    float tBi = __shfl_up(SBi, (unsigned)d, 64);
    if (lane >= d) {
      float nAr = SAr * tAr - SAi * tAi;
      float nAi = SAr * tAi + SAi * tAr;
      float nBr = SAr * tBr - SAi * tBi + SBr;
      float nBi = SAr * tBi + SAi * tBr + SBi;
      SAr = nAr; SAi = nAi; SBr = nBr; SBi = nBi;
    }
  }
  float EBr = __shfl_up(SBr, 1u, 64);
  float EBi = __shfl_up(SBi, 1u, 64);
  if (lane == 0) { EBr = 0.f; EBi = 0.f; }
#pragma unroll
  for (int u = 0; u < 4; u++) {
    float sr = pr[u] * EBr - pi[u] * EBi + qr[u];
    float si = pr[u] * EBi + pi[u] * EBr + qi[u];
    Carry[(size_t)(lane * 4 + u) * 1024 + c] = make_float2(sr, si);
  }
}

// ---------------- scan phase 3: fixup + ys + gate + out GEMM ----------------
__global__ __launch_bounds__(256) void k_scan3(const float2* __restrict__ Acum,
                                               const float2* __restrict__ Bloc,
                                               const float2* __restrict__ Carry,
                                               const float* __restrict__ Cin,
                                               const float* __restrict__ x,
                                               const float* __restrict__ gt,
                                               const float* __restrict__ Dp,
                                               const float* __restrict__ Wo,
                                               const float* __restrict__ bo,
                                               float* __restrict__ out) {
  __shared__ float2 carr_s[1024];
  __shared__ float2 C_s[8][32];
  __shared__ float Wo_s[1024];
  __shared__ float ht_s[8][32];
  int tid = threadIdx.x;
  int l0 = blockIdx.x * 8;
  int chunk = l0 >> 4;  // CLEN=16
#pragma unroll
  for (int i = 0; i < 4; i++)
    carr_s[i * 256 + tid] = Carry[(size_t)chunk * 1024 + i * 256 + tid];
  {
    int ll = tid >> 5, hh = tid & 31;
    C_s[ll][hh] = *(const float2*)(Cin + (size_t)(l0 + ll) * 64 + hh * 2);
  }
#pragma unroll
  for (int i = 0; i < 4; i++) Wo_s[i * 256 + tid] = Wo[i * 256 + tid];
  __syncthreads();

  int ll = tid >> 5, j = tid & 31;
  int l = l0 + ll;
  float ys = 0.f;
#pragma unroll 8
  for (int h = 0; h < 32; h++) {
    int c = h * 32 + j;
    float2 a = Acum[(size_t)l * 1024 + c];
    float2 b = Bloc[(size_t)l * 1024 + c];
    float2 s = carr_s[c];
    float xr = a.x * s.x - a.y * s.y + b.x;
    float xi = a.x * s.y + a.y * s.x + b.y;
    float2 cv = C_s[ll][h];
    ys = fmaf(cv.x, xr, ys);
    ys = fmaf(-cv.y, xi, ys);
  }
  float xv = x[l * 32 + j];
  float g = gt[l * 32 + j];
  float d = Dp[l];
  float ht = (1.0f - g) * (ys + d * xv) + g * xv;
  ht_s[ll][j] = ht;
  __syncthreads();
  float accv = bo[j];
#pragma unroll
  for (int jj = 0; jj < 32; jj++) accv = fmaf(ht_s[ll][jj], Wo_s[jj * 32 + j], accv);
  out[l * 32 + j] = accv;
}

extern "C" void kernel_launch(void* const* d_in, const int* in_sizes, int n_in,
                              void* d_out, int out_size, void* d_ws, size_t ws_size,
                              hipStream_t stream) {
  const float* x   = (const float*)d_in[0];
  const float* Lre = (const float*)d_in[1];
  const float* Lim = (const float*)d_in[2];
  const float* Bin = (const float*)d_in[3];
  const float* Cin = (const float*)d_in[4];
  const float* lst = (const float*)d_in[5];
  const float* Wb  = (const float*)d_in[6];
  const float* bb  = (const float*)d_in[7];
  const float* Wl  = (const float*)d_in[8];
  const float* bl  = (const float*)d_in[9];
  const float* cw  = (const float*)d_in[10];
  const float* cb  = (const float*)d_in[11];
  const float* Wg  = (const float*)d_in[12];
  const float* bg  = (const float*)d_in[13];
  const float* Wd  = (const float*)d_in[14];
  const float* bd  = (const float*)d_in[15];
  const float* Wo  = (const float*)d_in[16];
  const float* bo  = (const float*)d_in[17];
  float* out = (float*)d_out;

  char* ws = (char*)d_ws;
  size_t off = 0;
  auto alloc = [&](size_t bytes) {
    char* p = ws + off;
    off = (off + bytes + 255) & ~(size_t)255;
    return p;
  };
  float* consts          = (float*)alloc(6 * 1024 * 4);
  __hip_bfloat16* Bp     = (__hip_bfloat16*)alloc((size_t)(LSEQ + 3) * 1024 * 2);
  __hip_bfloat16* WT     = (__hip_bfloat16*)alloc((size_t)1024 * 4096 * 2);
  float* Lam             = (float*)alloc((size_t)LSEQ * 1024 * 4);
  float* Bact            = (float*)alloc((size_t)LSEQ * 1024 * 4);
  float* gt              = (float*)alloc((size_t)LSEQ * 32 * 4);
  float* Dp              = (float*)alloc((size_t)LSEQ * 4);
  float2* Acum           = (float2*)alloc((size_t)LSEQ * 1024 * 8);
  float2* Bloc           = (float2*)alloc((size_t)LSEQ * 1024 * 8);
  float2* Carry          = (float2*)alloc((size_t)NCHUNK * 1024 * 8);

  // zero-pad rows of Bp: row 0 (front), rows LSEQ+1, LSEQ+2 (back)
  hipMemsetAsync(Bp, 0, 1024 * 2, stream);
  hipMemsetAsync(Bp + (size_t)(LSEQ + 1) * 1024, 0, 2 * 1024 * 2, stream);

  k_const<<<1, 1024, 0, stream>>>(Lre, Lim, lst, consts);
  k_proj<<<LSEQ / 8, 256, 0, stream>>>(x, Wb, bb, Wl, bl, Wg, bg, Wd, bd, Bp, Lam, gt, Dp);
  k_transpose<<<dim3(128, 32), 256, 0, stream>>>(cw, WT);
  k_conv_gemm<<<dim3(1024 / BN, LSEQ / BM), 256, 0, stream>>>(Bp, WT, cb, Bact);
  k_scan1<<<4 * NCHUNK, 256, 0, stream>>>(consts, Lam, Bact, Bin, Acum, Bloc);
  k_scan2<<<1024, 64, 0, stream>>>(Acum, Bloc, Carry);
  k_scan3<<<LSEQ / 8, 256, 0, stream>>>(Acum, Bloc, Carry, Cin, x, gt, Dp, Wo, bo, out);
}